// Round 13
// baseline (95.434 us; speedup 1.0000x reference)
//
#include <hip/hip_runtime.h>

static constexpr int CH   = 128;   // CHANNELS
static constexpr int KPAD = 192;   // Atile row length (bf16) -> 384B rows

typedef __attribute__((ext_vector_type(8))) short bf16x8;
typedef __attribute__((ext_vector_type(4))) float f32x4;
typedef __attribute__((ext_vector_type(2))) unsigned int u32x2;

__device__ inline unsigned short f2bf(float x) {
    unsigned int u = __float_as_uint(x);
    unsigned int r = (u + 0x7fffu + ((u >> 16) & 1u)) >> 16;  // RNE
    return (unsigned short)r;
}
__device__ inline unsigned int pack2bf(float a, float b) {
    return (unsigned int)f2bf(a) | ((unsigned int)f2bf(b) << 16);
}

// ---------------------------------------------------------------------------
// idx2[e] = { src*64, dst*64 } byte offsets (quarter-rows = 64B).
// is64 detection fused (high words of first 128 elements all zero => int64).
// ---------------------------------------------------------------------------
__global__ __launch_bounds__(256) void idx_prep(
    const unsigned int* __restrict__ idxw, uint2* __restrict__ idx2,
    long long E, long long Epad) {
    unsigned nz = 0;
    const int lane = threadIdx.x & 63;
    for (int i = lane; i < 128; i += 64) nz |= idxw[2 * i + 1];
    const int is64 = (__ballot(nz != 0u) == 0ULL) ? 1 : 0;
    const long long stride = (long long)gridDim.x * blockDim.x;
    for (long long i = (long long)blockIdx.x * blockDim.x + threadIdx.x;
         i < Epad; i += stride) {
        uint2 v = make_uint2(0u, 0u);
        if (i < E) {
            const unsigned s = is64 ? idxw[2 * i] : idxw[i];
            const unsigned d = is64 ? idxw[2 * (E + i)] : idxw[E + i];
            v = make_uint2(s << 6, d << 6);
        }
        idx2[i] = v;
    }
}

// ---------------------------------------------------------------------------
// Wf: fragment-linear weight layout (proven r10). Logical W_col[c][k]:
//   k<128 : c<128 ? w1[k][c] : w1[128+k][c-128]
//   k=128 : +-w1[256][cc]  (-: P, +: Q)   k=129 : +-w1[257][cc]
//   k=130 : b1 (Q only)                   k>130 : 0
// ---------------------------------------------------------------------------
__global__ __launch_bounds__(256) void w1_prep2(const float* __restrict__ w1,
                                                const float* __restrict__ b1,
                                                unsigned short* __restrict__ Wf) {
    const int gid = blockIdx.x * 256 + threadIdx.x;  // 0..5119
    if (gid >= 4 * 5 * 4 * 64) return;
    const int lane = gid & 63;
    const int seg  = gid >> 6;
    const int m    = seg & 3;
    const int ks   = (seg >> 2) % 5;
    const int w    = seg / 20;
    const int c    = w * 64 + m * 16 + (lane & 15);
    const int k0   = ks * 32 + (lane >> 4) * 8;
    const bool isQ = c >= 128;
    const int cc   = c & 127;
    const float sgn = isQ ? 1.f : -1.f;
    unsigned int out[4];
#pragma unroll
    for (int h = 0; h < 4; ++h) {
        float v[2];
#pragma unroll
        for (int j = 0; j < 2; ++j) {
            const int k = k0 + 2 * h + j;
            float x;
            if (k < 128)       x = isQ ? w1[(size_t)(128 + k) * CH + cc]
                                       : w1[(size_t)k * CH + cc];
            else if (k == 128) x = sgn * w1[(size_t)(2 * CH) * CH + cc];
            else if (k == 129) x = sgn * w1[(size_t)(2 * CH + 1) * CH + cc];
            else if (k == 130) x = isQ ? b1[cc] : 0.f;
            else               x = 0.f;
            v[j] = x;
        }
        out[h] = pack2bf(v[0], v[1]);
    }
    *(uint4*)&Wf[(size_t)gid * 8] = make_uint4(out[0], out[1], out[2], out[3]);
}

// ---------------------------------------------------------------------------
// Node stage (r10 structure): 32 nodes x 256 cols, swapped-operand MFMA,
// K=160 (coords+bias folded). Output goes to 8 QUARTER buffers within PQall:
//   quarter q = (c<128 ? c>>5 : 4 + ((c&127)>>5)), each [N][32] bf16
//   (64B rows) at PQall + q*N*32.
// ---------------------------------------------------------------------------
__global__ __launch_bounds__(256) void node_mfma6(
    const float* __restrict__ tokens, const float* __restrict__ coords,
    const unsigned short* __restrict__ Wf, unsigned short* __restrict__ PQall,
    int N) {
    __shared__ unsigned short Atile[32 * KPAD];  // 12 KB, XOR-swizzled rows

    const int t    = threadIdx.x;
    const int l    = t & 63;
    const int wid  = t >> 6;
    const int n0   = blockIdx.x * 32;
    const int bl   = l & 15;
    const int bh   = l >> 4;

    // token chunks: 32 nodes x 16 chunks of 16B
#pragma unroll
    for (int it = 0; it < 2; ++it) {
        const int idx  = it * 256 + t;
        const int node = idx >> 4;
        const int cq   = idx & 15;
        float4 v0 = make_float4(0.f, 0.f, 0.f, 0.f);
        float4 v1 = v0;
        if (n0 + node < N) {
            const float* src = &tokens[(size_t)(n0 + node) * CH + cq * 8];
            v0 = *(const float4*)src;
            v1 = *(const float4*)(src + 4);
        }
        uint4 u;
        u.x = pack2bf(v0.x, v0.y);
        u.y = pack2bf(v0.z, v0.w);
        u.z = pack2bf(v1.x, v1.y);
        u.w = pack2bf(v1.z, v1.w);
        const int byte = node * 384 + ((cq * 16) ^ ((node & 7) << 4));
        *(uint4*)((char*)Atile + byte) = u;
    }
    // ext chunks: k=128..191 -> (cx, cy, 1, 0, ...)
    {
        const int node = t >> 3;
        const int ce   = t & 7;
        uint4 u = make_uint4(0u, 0u, 0u, 0u);
        if (ce == 0 && n0 + node < N) {
            const float cx = coords[2 * (n0 + node)];
            const float cy = coords[2 * (n0 + node) + 1];
            u.x = pack2bf(cx, cy);
            u.y = pack2bf(1.f, 0.f);
        }
        const int byte = node * 384 + (((16 + ce) * 16) ^ ((node & 7) << 4));
        *(uint4*)((char*)Atile + byte) = u;
    }
    __syncthreads();

    f32x4 acc[4][2];
#pragma unroll
    for (int m = 0; m < 4; ++m)
#pragma unroll
        for (int n = 0; n < 2; ++n) acc[m][n] = (f32x4){0.f, 0.f, 0.f, 0.f};

#pragma unroll
    for (int ks = 0; ks < 5; ++ks) {
        bf16x8 wfrag[4], tfrag[2];
#pragma unroll
        for (int m = 0; m < 4; ++m)
            wfrag[m] = *(const bf16x8*)&Wf[(size_t)(((wid * 5 + ks) * 4 + m) * 64
                                                    + l) * 8];
#pragma unroll
        for (int n = 0; n < 2; ++n) {
            const int row  = n * 16 + bl;
            const int byte = row * 384 + ((ks * 64 + bh * 16) ^ ((row & 7) << 4));
            tfrag[n] = *(const bf16x8*)((const char*)Atile + byte);
        }
#pragma unroll
        for (int m = 0; m < 4; ++m)
#pragma unroll
            for (int n = 0; n < 2; ++n)
                acc[m][n] = __builtin_amdgcn_mfma_f32_16x16x32_bf16(
                    wfrag[m], tfrag[n], acc[m][n], 0, 0, 0);
    }

    // stores: D rows = output cols c = wid*64 + m*16 + bh*4 (+0..3)
#pragma unroll
    for (int m = 0; m < 4; ++m) {
        const int c = wid * 64 + m * 16 + bh * 4;
        const int q = (c < CH) ? (c >> 5) : (4 + ((c & 127) >> 5));
        unsigned short* dst = PQall + (size_t)q * N * 32;
        const int col = c & 31;
#pragma unroll
        for (int n = 0; n < 2; ++n) {
            const int node = n0 + n * 16 + bl;
            if (node < N) {
                uint2 val;
                val.x = pack2bf(acc[m][n][0], acc[m][n][1]);
                val.y = pack2bf(acc[m][n][2], acc[m][n][3]);
                *(uint2*)&dst[(size_t)node * 32 + col] = val;
            }
        }
    }
}

// ---------------------------------------------------------------------------
// Edge pass over one channel quarter (32 ch, 64B rows = ONE cache line).
// 4-lane group owns 4 edges/iter; each row gather = 4 lanes x 16B = 64B = one
// merged L2 request. Per-pass working set 6.4 MB. Partial chain in fp32:
// pass0 store, pass1/2 rmw, pass3 add+bias -> out (all nontemporal).
// ---------------------------------------------------------------------------
template <int PASS>
__global__ __launch_bounds__(256) void edge_pass4(
    const unsigned int* __restrict__ idx2w, const unsigned short* __restrict__ PQall,
    const float* __restrict__ w2, const float* __restrict__ b2,
    float* __restrict__ partial, float* __restrict__ out, long long E, int N) {
    const int t  = threadIdx.x;
    const int gl = t & 3;
    const long long nq = (E + 3) >> 2;                       // edge quads
    const long long g0 = (long long)blockIdx.x * 64 + (t >> 2);
    const long long ng = (long long)gridDim.x * 64;
    const float4 wa = *(const float4*)&w2[PASS * 32 + gl * 8];
    const float4 wb = *(const float4*)&w2[PASS * 32 + gl * 8 + 4];
    const float bias = b2[0];
    const char* P = (const char*)(PQall + (size_t)PASS * N * 32);
    const char* Q = (const char*)(PQall + (size_t)(4 + PASS) * N * 32);

    for (long long q = g0; q < nq; q += ng) {
        const long long e0 = q << 2;
        const u32x2 iv = __builtin_nontemporal_load(
            (const u32x2*)&idx2w[(e0 + gl) * 2]);
        unsigned soff[4], doff[4];
#pragma unroll
        for (int j = 0; j < 4; ++j) {
            soff[j] = __shfl(iv.x, j, 4);
            doff[j] = __shfl(iv.y, j, 4);
        }
        uint4 pv[4], qv[4];
#pragma unroll
        for (int j = 0; j < 4; ++j)
            pv[j] = *(const uint4*)(P + soff[j] + 16 * gl);
#pragma unroll
        for (int j = 0; j < 4; ++j)
            qv[j] = *(const uint4*)(Q + doff[j] + 16 * gl);

        float part[4];
#pragma unroll
        for (int j = 0; j < 4; ++j) {
            const float wv[8] = {wa.x, wa.y, wa.z, wa.w, wb.x, wb.y, wb.z, wb.w};
            const unsigned pw[4] = {pv[j].x, pv[j].y, pv[j].z, pv[j].w};
            const unsigned qw[4] = {qv[j].x, qv[j].y, qv[j].z, qv[j].w};
            float acc = 0.f;
#pragma unroll
            for (int i = 0; i < 4; ++i) {
                const float plo = __uint_as_float(pw[i] << 16);
                const float phi = __uint_as_float(pw[i] & 0xffff0000u);
                const float qlo = __uint_as_float(qw[i] << 16);
                const float qhi = __uint_as_float(qw[i] & 0xffff0000u);
                acc = fmaf(fmaxf(plo + qlo, 0.f), wv[2 * i], acc);
                acc = fmaf(fmaxf(phi + qhi, 0.f), wv[2 * i + 1], acc);
            }
            part[j] = acc;
        }

        // width-4 butterfly with packing; lane gl ends with edge (e0+gl)'s sum
        float t0 = part[0] + __shfl_xor(part[0], 1);
        float t1 = part[1] + __shfl_xor(part[1], 1);
        float t2 = part[2] + __shfl_xor(part[2], 1);
        float t3 = part[3] + __shfl_xor(part[3], 1);
        float a0 = (gl & 1) ? t1 : t0;
        float a1 = (gl & 1) ? t3 : t2;
        a0 += __shfl_xor(a0, 2);
        a1 += __shfl_xor(a1, 2);
        const float c = (gl & 2) ? a1 : a0;

        const long long e = e0 + gl;
        if (e < E) {
            if (PASS == 0) {
                __builtin_nontemporal_store(c, &partial[e]);
            } else if (PASS < 3) {
                const float prev = __builtin_nontemporal_load(&partial[e]);
                __builtin_nontemporal_store(prev + c, &partial[e]);
            } else {
                out[e] = __builtin_nontemporal_load(&partial[e]) + c + bias;
            }
        }
    }
}

extern "C" void kernel_launch(void* const* d_in, const int* in_sizes, int n_in,
                              void* d_out, int out_size, void* d_ws,
                              size_t ws_size, hipStream_t stream) {
    const float* tokens = (const float*)d_in[0];
    const float* coords = (const float*)d_in[1];
    const unsigned int* idxw = (const unsigned int*)d_in[2];
    const float* w1 = (const float*)d_in[3];
    const float* b1 = (const float*)d_in[4];
    const float* w2 = (const float*)d_in[5];
    const float* b2 = (const float*)d_in[6];
    float* out = (float*)d_out;

    const int N = in_sizes[0] / CH;       // 50000
    const long long E = in_sizes[2] / 2;  // 800000
    const long long Epad = ((E + 3) >> 2) << 2;

    unsigned short* PQall = (unsigned short*)d_ws;           // 8 x [N][32]
    uint2* idx2 = (uint2*)(PQall + (size_t)N * CH * 2);
    unsigned short* Wf = (unsigned short*)(idx2 + Epad);     // 80 KB
    float* partial = (float*)(Wf + 5120 * 8);                // Epad floats

    idx_prep<<<1024, 256, 0, stream>>>(idxw, idx2, E, Epad);
    w1_prep2<<<20, 256, 0, stream>>>(w1, b1, Wf);

    node_mfma6<<<(N + 31) / 32, 256, 0, stream>>>(tokens, coords, Wf, PQall, N);

    const unsigned int* idx2w = (const unsigned int*)idx2;
    edge_pass4<0><<<4096, 256, 0, stream>>>(idx2w, PQall, w2, b2, partial, out, E, N);
    edge_pass4<1><<<4096, 256, 0, stream>>>(idx2w, PQall, w2, b2, partial, out, E, N);
    edge_pass4<2><<<4096, 256, 0, stream>>>(idx2w, PQall, w2, b2, partial, out, E, N);
    edge_pass4<3><<<4096, 256, 0, stream>>>(idx2w, PQall, w2, b2, partial, out, E, N);
}

// Round 14
// 71.979 us; speedup vs baseline: 1.3259x; 1.3259x over previous
//
#include <hip/hip_runtime.h>

static constexpr int CH   = 128;   // CHANNELS
static constexpr int KPAD = 192;   // Atile row length (bf16) -> 384B rows

typedef __attribute__((ext_vector_type(8))) short bf16x8;
typedef __attribute__((ext_vector_type(4))) float f32x4;
typedef __attribute__((ext_vector_type(2))) unsigned int u32x2;

__device__ inline unsigned short f2bf(float x) {
    unsigned int u = __float_as_uint(x);
    unsigned int r = (u + 0x7fffu + ((u >> 16) & 1u)) >> 16;  // RNE
    return (unsigned short)r;
}
__device__ inline unsigned int pack2bf(float a, float b) {
    return (unsigned int)f2bf(a) | ((unsigned int)f2bf(b) << 16);
}

// ---------------------------------------------------------------------------
// Fused prep kernel.
//  blocks 0..19   : Wf fragment-linear weight layout (proven r10)
//  blocks 20..1043: idx2[e] = { src*128, dst*128 } (128B half-row offsets);
//                   is64 detect fused (high words of first 128 elems).
// ---------------------------------------------------------------------------
__global__ __launch_bounds__(256) void prep_all(
    const float* __restrict__ w1, const float* __restrict__ b1,
    unsigned short* __restrict__ Wf, const unsigned int* __restrict__ idxw,
    uint2* __restrict__ idx2, long long E, long long Epad) {
    const int t = threadIdx.x;
    if (blockIdx.x < 20) {
        const int gid = blockIdx.x * 256 + t;  // 0..5119
        const int lane = gid & 63;
        const int seg  = gid >> 6;
        const int m    = seg & 3;
        const int ks   = (seg >> 2) % 5;
        const int w    = seg / 20;
        const int c    = w * 64 + m * 16 + (lane & 15);
        const int k0   = ks * 32 + (lane >> 4) * 8;
        const bool isQ = c >= 128;
        const int cc   = c & 127;
        const float sgn = isQ ? 1.f : -1.f;
        unsigned int out[4];
#pragma unroll
        for (int h = 0; h < 4; ++h) {
            float v[2];
#pragma unroll
            for (int j = 0; j < 2; ++j) {
                const int k = k0 + 2 * h + j;
                float x;
                if (k < 128)       x = isQ ? w1[(size_t)(128 + k) * CH + cc]
                                           : w1[(size_t)k * CH + cc];
                else if (k == 128) x = sgn * w1[(size_t)(2 * CH) * CH + cc];
                else if (k == 129) x = sgn * w1[(size_t)(2 * CH + 1) * CH + cc];
                else if (k == 130) x = isQ ? b1[cc] : 0.f;
                else               x = 0.f;
                v[j] = x;
            }
            out[h] = pack2bf(v[0], v[1]);
        }
        *(uint4*)&Wf[(size_t)gid * 8] = make_uint4(out[0], out[1], out[2], out[3]);
        return;
    }
    // ---- idx part ----
    unsigned nz = 0;
    const int lane = t & 63;
    for (int i = lane; i < 128; i += 64) nz |= idxw[2 * i + 1];
    const int is64 = (__ballot(nz != 0u) == 0ULL) ? 1 : 0;
    const long long bid = blockIdx.x - 20;
    const long long stride = (long long)(gridDim.x - 20) * 256;
    for (long long i = bid * 256 + t; i < Epad; i += stride) {
        uint2 v = make_uint2(0u, 0u);
        if (i < E) {
            const unsigned s = is64 ? idxw[2 * i] : idxw[i];
            const unsigned d = is64 ? idxw[2 * (E + i)] : idxw[E + i];
            v = make_uint2(s << 7, d << 7);
        }
        idx2[i] = v;
    }
}

// ---------------------------------------------------------------------------
// Node stage: 32 nodes x 256 cols, swapped-operand MFMA, K=160 (coords+bias
// folded), Wf fragment-linear loads. NEW: epilogue goes through a 16KB
// swizzled LDS out-tile so global stores are coalesced 16B chunks
// (store line-requests ~3.2M -> ~0.4M). Output: 4 half-buffers [N][64] bf16.
// ---------------------------------------------------------------------------
__global__ __launch_bounds__(256) void node_mfma7(
    const float* __restrict__ tokens, const float* __restrict__ coords,
    const unsigned short* __restrict__ Wf, unsigned short* __restrict__ Plo,
    unsigned short* __restrict__ Phi, unsigned short* __restrict__ Qlo,
    unsigned short* __restrict__ Qhi, int N) {
    __shared__ unsigned short Atile[32 * KPAD];   // 12 KB, XOR-swizzled rows
    __shared__ unsigned short Otile[32 * 256];    // 16 KB, XOR-swizzled rows

    const int t    = threadIdx.x;
    const int l    = t & 63;
    const int wid  = t >> 6;
    const int n0   = blockIdx.x * 32;
    const int bl   = l & 15;
    const int bh   = l >> 4;

    // token chunks: 32 nodes x 16 chunks of 16B
#pragma unroll
    for (int it = 0; it < 2; ++it) {
        const int idx  = it * 256 + t;
        const int node = idx >> 4;
        const int cq   = idx & 15;
        float4 v0 = make_float4(0.f, 0.f, 0.f, 0.f);
        float4 v1 = v0;
        if (n0 + node < N) {
            const float* src = &tokens[(size_t)(n0 + node) * CH + cq * 8];
            v0 = *(const float4*)src;
            v1 = *(const float4*)(src + 4);
        }
        uint4 u;
        u.x = pack2bf(v0.x, v0.y);
        u.y = pack2bf(v0.z, v0.w);
        u.z = pack2bf(v1.x, v1.y);
        u.w = pack2bf(v1.z, v1.w);
        const int byte = node * 384 + ((cq * 16) ^ ((node & 7) << 4));
        *(uint4*)((char*)Atile + byte) = u;
    }
    // ext chunks: k=128..191 -> (cx, cy, 1, 0, ...)
    {
        const int node = t >> 3;
        const int ce   = t & 7;
        uint4 u = make_uint4(0u, 0u, 0u, 0u);
        if (ce == 0 && n0 + node < N) {
            const float cx = coords[2 * (n0 + node)];
            const float cy = coords[2 * (n0 + node) + 1];
            u.x = pack2bf(cx, cy);
            u.y = pack2bf(1.f, 0.f);
        }
        const int byte = node * 384 + (((16 + ce) * 16) ^ ((node & 7) << 4));
        *(uint4*)((char*)Atile + byte) = u;
    }
    __syncthreads();

    f32x4 acc[4][2];
#pragma unroll
    for (int m = 0; m < 4; ++m)
#pragma unroll
        for (int n = 0; n < 2; ++n) acc[m][n] = (f32x4){0.f, 0.f, 0.f, 0.f};

#pragma unroll
    for (int ks = 0; ks < 5; ++ks) {
        bf16x8 wfrag[4], tfrag[2];
#pragma unroll
        for (int m = 0; m < 4; ++m)
            wfrag[m] = *(const bf16x8*)&Wf[(size_t)(((wid * 5 + ks) * 4 + m) * 64
                                                    + l) * 8];
#pragma unroll
        for (int n = 0; n < 2; ++n) {
            const int row  = n * 16 + bl;
            const int byte = row * 384 + ((ks * 64 + bh * 16) ^ ((row & 7) << 4));
            tfrag[n] = *(const bf16x8*)((const char*)Atile + byte);
        }
#pragma unroll
        for (int m = 0; m < 4; ++m)
#pragma unroll
            for (int n = 0; n < 2; ++n)
                acc[m][n] = __builtin_amdgcn_mfma_f32_16x16x32_bf16(
                    wfrag[m], tfrag[n], acc[m][n], 0, 0, 0);
    }

    // ---- epilogue: fragments -> swizzled Otile (node-major rows) ----
#pragma unroll
    for (int m = 0; m < 4; ++m) {
        const int col = wid * 64 + m * 16 + bh * 4;   // 0..255
#pragma unroll
        for (int n = 0; n < 2; ++n) {
            const int node = n * 16 + bl;             // local 0..31
            uint2 val;
            val.x = pack2bf(acc[m][n][0], acc[m][n][1]);
            val.y = pack2bf(acc[m][n][2], acc[m][n][3]);
            const int byte = node * 512 + ((col * 2) ^ ((node & 7) << 4));
            *(uint2*)((char*)Otile + byte) = val;
        }
    }
    __syncthreads();

    // ---- coalesced store: 32B per thread-iter, seg>>2 selects buffer ----
#pragma unroll
    for (int it = 0; it < 2; ++it) {
        const int idx  = it * 256 + t;   // 0..511
        const int node = idx >> 4;       // local 0..31
        const int seg  = idx & 15;       // 16 segs x 32B (16 cols)
        const int gn   = n0 + node;
        if (gn < N) {
            unsigned short* dst = (seg < 4) ? Plo : (seg < 8) ? Phi
                                  : (seg < 12) ? Qlo : Qhi;
            const int colq = (seg & 3) * 16;
#pragma unroll
            for (int h = 0; h < 2; ++h) {
                const int byte = node * 512 +
                                 ((seg * 32 + h * 16) ^ ((node & 7) << 4));
                const uint4 v = *(const uint4*)((const char*)Otile + byte);
                *(uint4*)&dst[(size_t)gn * 64 + colq + h * 8] = v;
            }
        }
    }
}

// ---------------------------------------------------------------------------
// Edge pass over one channel half (64 ch, 128B rows) — r12-proven structure.
// 8-lane group owns 4 edges/iter; 8 gathers of uint4 (8 lanes x 16B = row).
// Pass 0 stores fp32 partials (nontemporal); pass 1 adds + bias -> out.
// ---------------------------------------------------------------------------
template <int PASS>
__global__ __launch_bounds__(256) void edge_pass(
    const unsigned int* __restrict__ idx2w, const unsigned short* __restrict__ Pb,
    const unsigned short* __restrict__ Qb, const float* __restrict__ w2,
    const float* __restrict__ b2, float* __restrict__ partial,
    float* __restrict__ out, long long E) {
    const int t  = threadIdx.x;
    const int gl = t & 7;
    const long long nq = (E + 3) >> 2;                       // edge quads
    const long long g0 = (long long)blockIdx.x * 32 + (t >> 3);
    const long long ng = (long long)gridDim.x * 32;
    const float4 wa = *(const float4*)&w2[PASS * 64 + gl * 8];
    const float4 wb = *(const float4*)&w2[PASS * 64 + gl * 8 + 4];
    const float bias = b2[0];
    const char* P = (const char*)Pb;
    const char* Q = (const char*)Qb;

    for (long long q = g0; q < nq; q += ng) {
        const long long e0 = q << 2;
        const u32x2 iv = __builtin_nontemporal_load(
            (const u32x2*)&idx2w[(e0 + (gl & 3)) * 2]);
        unsigned soff[4], doff[4];
#pragma unroll
        for (int j = 0; j < 4; ++j) {
            soff[j] = __shfl(iv.x, j, 8);
            doff[j] = __shfl(iv.y, j, 8);
        }
        uint4 pv[4], qv[4];
#pragma unroll
        for (int j = 0; j < 4; ++j)
            pv[j] = *(const uint4*)(P + soff[j] + 16 * gl);
#pragma unroll
        for (int j = 0; j < 4; ++j)
            qv[j] = *(const uint4*)(Q + doff[j] + 16 * gl);

        float part[4];
#pragma unroll
        for (int j = 0; j < 4; ++j) {
            const float wv[8] = {wa.x, wa.y, wa.z, wa.w, wb.x, wb.y, wb.z, wb.w};
            const unsigned pw[4] = {pv[j].x, pv[j].y, pv[j].z, pv[j].w};
            const unsigned qw[4] = {qv[j].x, qv[j].y, qv[j].z, qv[j].w};
            float acc = 0.f;
#pragma unroll
            for (int i = 0; i < 4; ++i) {
                const float plo = __uint_as_float(pw[i] << 16);
                const float phi = __uint_as_float(pw[i] & 0xffff0000u);
                const float qlo = __uint_as_float(qw[i] << 16);
                const float qhi = __uint_as_float(qw[i] & 0xffff0000u);
                acc = fmaf(fmaxf(plo + qlo, 0.f), wv[2 * i], acc);
                acc = fmaf(fmaxf(phi + qhi, 0.f), wv[2 * i + 1], acc);
            }
            part[j] = acc;
        }

        // width-8 butterfly with packing; lane gl<4 ends with edge gl's sum
        float t0 = part[0] + __shfl_xor(part[0], 1);
        float t1 = part[1] + __shfl_xor(part[1], 1);
        float t2 = part[2] + __shfl_xor(part[2], 1);
        float t3 = part[3] + __shfl_xor(part[3], 1);
        float a0 = (gl & 1) ? t1 : t0;
        float a1 = (gl & 1) ? t3 : t2;
        a0 += __shfl_xor(a0, 2);
        a1 += __shfl_xor(a1, 2);
        float c = (gl & 2) ? a1 : a0;
        c += __shfl_xor(c, 4);

        const long long e = e0 + gl;
        if (gl < 4 && e < E) {
            if (PASS == 0) {
                __builtin_nontemporal_store(c, &partial[e]);
            } else {
                out[e] = __builtin_nontemporal_load(&partial[e]) + c + bias;
            }
        }
    }
}

extern "C" void kernel_launch(void* const* d_in, const int* in_sizes, int n_in,
                              void* d_out, int out_size, void* d_ws,
                              size_t ws_size, hipStream_t stream) {
    const float* tokens = (const float*)d_in[0];
    const float* coords = (const float*)d_in[1];
    const unsigned int* idxw = (const unsigned int*)d_in[2];
    const float* w1 = (const float*)d_in[3];
    const float* b1 = (const float*)d_in[4];
    const float* w2 = (const float*)d_in[5];
    const float* b2 = (const float*)d_in[6];
    float* out = (float*)d_out;

    const int N = in_sizes[0] / CH;       // 50000
    const long long E = in_sizes[2] / 2;  // 800000
    const long long Epad = ((E + 3) >> 2) << 2;

    unsigned short* Plo = (unsigned short*)d_ws;   // [N][64] each
    unsigned short* Phi = Plo + (size_t)N * 64;
    unsigned short* Qlo = Phi + (size_t)N * 64;
    unsigned short* Qhi = Qlo + (size_t)N * 64;
    uint2* idx2 = (uint2*)(Qhi + (size_t)N * 64);
    unsigned short* Wf = (unsigned short*)(idx2 + Epad);   // 80 KB
    float* partial = (float*)(Wf + 5120 * 8);              // Epad floats

    prep_all<<<1044, 256, 0, stream>>>(w1, b1, Wf, idxw, idx2, E, Epad);

    node_mfma7<<<(N + 31) / 32, 256, 0, stream>>>(tokens, coords, Wf,
                                                  Plo, Phi, Qlo, Qhi, N);

    edge_pass<0><<<4096, 256, 0, stream>>>((const unsigned int*)idx2, Plo, Qlo,
                                           w2, b2, partial, out, E);
    edge_pass<1><<<4096, 256, 0, stream>>>((const unsigned int*)idx2, Phi, Qhi,
                                           w2, b2, partial, out, E);
}

// Round 15
// 68.496 us; speedup vs baseline: 1.3933x; 1.0509x over previous
//
#include <hip/hip_runtime.h>

static constexpr int CH   = 128;   // CHANNELS
static constexpr int KPAD = 192;   // Atile row length (bf16) -> 384B rows

typedef __attribute__((ext_vector_type(8))) short bf16x8;
typedef __attribute__((ext_vector_type(4))) float f32x4;
typedef __attribute__((ext_vector_type(2))) unsigned int u32x2;

__device__ inline unsigned short f2bf(float x) {
    unsigned int u = __float_as_uint(x);
    unsigned int r = (u + 0x7fffu + ((u >> 16) & 1u)) >> 16;  // RNE
    return (unsigned short)r;
}
__device__ inline unsigned int pack2bf(float a, float b) {
    return (unsigned int)f2bf(a) | ((unsigned int)f2bf(b) << 16);
}

// ---------------------------------------------------------------------------
// Fused prep kernel.
//  blocks 0..19      : Wf fragment-linear weight layout (proven r10)
//  blocks 20..801    : out[e] = 0.0f zero-fill (atomic accumulation base)
//  blocks 802..1825  : idx2[e] = { src*128, dst*128 } (128B half-row offsets);
//                      is64 detect fused (high words of first 128 elems).
// ---------------------------------------------------------------------------
__global__ __launch_bounds__(256) void prep_all(
    const float* __restrict__ w1, const float* __restrict__ b1,
    unsigned short* __restrict__ Wf, const unsigned int* __restrict__ idxw,
    uint2* __restrict__ idx2, float* __restrict__ out,
    long long E, long long Epad) {
    const int t = threadIdx.x;
    if (blockIdx.x < 20) {
        const int gid = blockIdx.x * 256 + t;  // 0..5119
        const int lane = gid & 63;
        const int seg  = gid >> 6;
        const int m    = seg & 3;
        const int ks   = (seg >> 2) % 5;
        const int w    = seg / 20;
        const int c    = w * 64 + m * 16 + (lane & 15);
        const int k0   = ks * 32 + (lane >> 4) * 8;
        const bool isQ = c >= 128;
        const int cc   = c & 127;
        const float sgn = isQ ? 1.f : -1.f;
        unsigned int outw[4];
#pragma unroll
        for (int h = 0; h < 4; ++h) {
            float v[2];
#pragma unroll
            for (int j = 0; j < 2; ++j) {
                const int k = k0 + 2 * h + j;
                float x;
                if (k < 128)       x = isQ ? w1[(size_t)(128 + k) * CH + cc]
                                           : w1[(size_t)k * CH + cc];
                else if (k == 128) x = sgn * w1[(size_t)(2 * CH) * CH + cc];
                else if (k == 129) x = sgn * w1[(size_t)(2 * CH + 1) * CH + cc];
                else if (k == 130) x = isQ ? b1[cc] : 0.f;
                else               x = 0.f;
                v[j] = x;
            }
            outw[h] = pack2bf(v[0], v[1]);
        }
        *(uint4*)&Wf[(size_t)gid * 8] =
            make_uint4(outw[0], outw[1], outw[2], outw[3]);
        return;
    }
    if (blockIdx.x < 802) {
        // zero-fill out: block covers 1024 floats
        const long long base = (long long)(blockIdx.x - 20) * 1024 + t * 4;
        if (base + 3 < E) {
            *(float4*)&out[base] = make_float4(0.f, 0.f, 0.f, 0.f);
        } else {
            for (long long i = base; i < E; ++i) out[i] = 0.f;
        }
        return;
    }
    // ---- idx part ----
    unsigned nz = 0;
    const int lane = t & 63;
    for (int i = lane; i < 128; i += 64) nz |= idxw[2 * i + 1];
    const int is64 = (__ballot(nz != 0u) == 0ULL) ? 1 : 0;
    const long long bid = blockIdx.x - 802;
    const long long stride = (long long)(gridDim.x - 802) * 256;
    for (long long i = bid * 256 + t; i < Epad; i += stride) {
        uint2 v = make_uint2(0u, 0u);
        if (i < E) {
            const unsigned s = is64 ? idxw[2 * i] : idxw[i];
            const unsigned d = is64 ? idxw[2 * (E + i)] : idxw[E + i];
            v = make_uint2(s << 7, d << 7);
        }
        idx2[i] = v;
    }
}

// ---------------------------------------------------------------------------
// Node stage (r14-proven): 32 nodes x 256 cols, swapped-operand MFMA, K=160
// (coords+bias folded), Wf fragment-linear loads, swizzled LDS out-tile ->
// coalesced 16B stores. Output: 4 half-buffers [N][64] bf16 (128B rows).
// ---------------------------------------------------------------------------
__global__ __launch_bounds__(256) void node_mfma7(
    const float* __restrict__ tokens, const float* __restrict__ coords,
    const unsigned short* __restrict__ Wf, unsigned short* __restrict__ Plo,
    unsigned short* __restrict__ Phi, unsigned short* __restrict__ Qlo,
    unsigned short* __restrict__ Qhi, int N) {
    __shared__ unsigned short Atile[32 * KPAD];   // 12 KB, XOR-swizzled rows
    __shared__ unsigned short Otile[32 * 256];    // 16 KB, XOR-swizzled rows

    const int t    = threadIdx.x;
    const int l    = t & 63;
    const int wid  = t >> 6;
    const int n0   = blockIdx.x * 32;
    const int bl   = l & 15;
    const int bh   = l >> 4;

    // token chunks: 32 nodes x 16 chunks of 16B
#pragma unroll
    for (int it = 0; it < 2; ++it) {
        const int idx  = it * 256 + t;
        const int node = idx >> 4;
        const int cq   = idx & 15;
        float4 v0 = make_float4(0.f, 0.f, 0.f, 0.f);
        float4 v1 = v0;
        if (n0 + node < N) {
            const float* src = &tokens[(size_t)(n0 + node) * CH + cq * 8];
            v0 = *(const float4*)src;
            v1 = *(const float4*)(src + 4);
        }
        uint4 u;
        u.x = pack2bf(v0.x, v0.y);
        u.y = pack2bf(v0.z, v0.w);
        u.z = pack2bf(v1.x, v1.y);
        u.w = pack2bf(v1.z, v1.w);
        const int byte = node * 384 + ((cq * 16) ^ ((node & 7) << 4));
        *(uint4*)((char*)Atile + byte) = u;
    }
    // ext chunks: k=128..191 -> (cx, cy, 1, 0, ...)
    {
        const int node = t >> 3;
        const int ce   = t & 7;
        uint4 u = make_uint4(0u, 0u, 0u, 0u);
        if (ce == 0 && n0 + node < N) {
            const float cx = coords[2 * (n0 + node)];
            const float cy = coords[2 * (n0 + node) + 1];
            u.x = pack2bf(cx, cy);
            u.y = pack2bf(1.f, 0.f);
        }
        const int byte = node * 384 + (((16 + ce) * 16) ^ ((node & 7) << 4));
        *(uint4*)((char*)Atile + byte) = u;
    }
    __syncthreads();

    f32x4 acc[4][2];
#pragma unroll
    for (int m = 0; m < 4; ++m)
#pragma unroll
        for (int n = 0; n < 2; ++n) acc[m][n] = (f32x4){0.f, 0.f, 0.f, 0.f};

#pragma unroll
    for (int ks = 0; ks < 5; ++ks) {
        bf16x8 wfrag[4], tfrag[2];
#pragma unroll
        for (int m = 0; m < 4; ++m)
            wfrag[m] = *(const bf16x8*)&Wf[(size_t)(((wid * 5 + ks) * 4 + m) * 64
                                                    + l) * 8];
#pragma unroll
        for (int n = 0; n < 2; ++n) {
            const int row  = n * 16 + bl;
            const int byte = row * 384 + ((ks * 64 + bh * 16) ^ ((row & 7) << 4));
            tfrag[n] = *(const bf16x8*)((const char*)Atile + byte);
        }
#pragma unroll
        for (int m = 0; m < 4; ++m)
#pragma unroll
            for (int n = 0; n < 2; ++n)
                acc[m][n] = __builtin_amdgcn_mfma_f32_16x16x32_bf16(
                    wfrag[m], tfrag[n], acc[m][n], 0, 0, 0);
    }

    // ---- epilogue: fragments -> swizzled Otile (node-major rows) ----
#pragma unroll
    for (int m = 0; m < 4; ++m) {
        const int col = wid * 64 + m * 16 + bh * 4;   // 0..255
#pragma unroll
        for (int n = 0; n < 2; ++n) {
            const int node = n * 16 + bl;             // local 0..31
            uint2 val;
            val.x = pack2bf(acc[m][n][0], acc[m][n][1]);
            val.y = pack2bf(acc[m][n][2], acc[m][n][3]);
            const int byte = node * 512 + ((col * 2) ^ ((node & 7) << 4));
            *(uint2*)((char*)Otile + byte) = val;
        }
    }
    __syncthreads();

    // ---- coalesced store: 32B per thread-iter, seg>>2 selects buffer ----
#pragma unroll
    for (int it = 0; it < 2; ++it) {
        const int idx  = it * 256 + t;   // 0..511
        const int node = idx >> 4;       // local 0..31
        const int seg  = idx & 15;       // 16 segs x 32B (16 cols)
        const int gn   = n0 + node;
        if (gn < N) {
            unsigned short* dst = (seg < 4) ? Plo : (seg < 8) ? Phi
                                  : (seg < 12) ? Qlo : Qhi;
            const int colq = (seg & 3) * 16;
#pragma unroll
            for (int h = 0; h < 2; ++h) {
                const int byte = node * 512 +
                                 ((seg * 32 + h * 16) ^ ((node & 7) << 4));
                const uint4 v = *(const uint4*)((const char*)Otile + byte);
                *(uint4*)&dst[(size_t)gn * 64 + colq + h * 8] = v;
            }
        }
    }
}

// ---------------------------------------------------------------------------
// Fused edge kernel: half = blockIdx&1; XCD = blockIdx&7, so each XCD only
// ever touches ONE channel half (even XCDs: half 0, odd: half 1) -> per-XCD
// working set stays 12.8 MB while both halves run concurrently. Each edge
// gets exactly two atomicAdds onto a zero base (bitwise-deterministic;
// bias folded into the half-1 addend). 8-lane group owns 4 edges/iter.
// ---------------------------------------------------------------------------
__global__ __launch_bounds__(256) void edge_fused(
    const unsigned int* __restrict__ idx2w,
    const unsigned short* __restrict__ Plo, const unsigned short* __restrict__ Phi,
    const unsigned short* __restrict__ Qlo, const unsigned short* __restrict__ Qhi,
    const float* __restrict__ w2, const float* __restrict__ b2,
    float* __restrict__ out, long long E) {
    const int half = blockIdx.x & 1;
    const int t  = threadIdx.x;
    const int gl = t & 7;
    const long long nq = (E + 3) >> 2;                       // edge quads
    const long long pb = blockIdx.x >> 1;
    const long long g0 = pb * 32 + (t >> 3);
    const long long ng = (long long)(gridDim.x >> 1) * 32;
    const float4 wa = *(const float4*)&w2[half * 64 + gl * 8];
    const float4 wb = *(const float4*)&w2[half * 64 + gl * 8 + 4];
    const float bias = half ? b2[0] : 0.f;
    const char* P = (const char*)(half ? Phi : Plo);
    const char* Q = (const char*)(half ? Qhi : Qlo);

    for (long long q = g0; q < nq; q += ng) {
        const long long e0 = q << 2;
        const u32x2 iv = __builtin_nontemporal_load(
            (const u32x2*)&idx2w[(e0 + (gl & 3)) * 2]);
        unsigned soff[4], doff[4];
#pragma unroll
        for (int j = 0; j < 4; ++j) {
            soff[j] = __shfl(iv.x, j, 8);
            doff[j] = __shfl(iv.y, j, 8);
        }
        uint4 pv[4], qv[4];
#pragma unroll
        for (int j = 0; j < 4; ++j)
            pv[j] = *(const uint4*)(P + soff[j] + 16 * gl);
#pragma unroll
        for (int j = 0; j < 4; ++j)
            qv[j] = *(const uint4*)(Q + doff[j] + 16 * gl);

        float part[4];
#pragma unroll
        for (int j = 0; j < 4; ++j) {
            const float wv[8] = {wa.x, wa.y, wa.z, wa.w, wb.x, wb.y, wb.z, wb.w};
            const unsigned pw[4] = {pv[j].x, pv[j].y, pv[j].z, pv[j].w};
            const unsigned qw[4] = {qv[j].x, qv[j].y, qv[j].z, qv[j].w};
            float acc = 0.f;
#pragma unroll
            for (int i = 0; i < 4; ++i) {
                const float plo = __uint_as_float(pw[i] << 16);
                const float phi = __uint_as_float(pw[i] & 0xffff0000u);
                const float qlo = __uint_as_float(qw[i] << 16);
                const float qhi = __uint_as_float(qw[i] & 0xffff0000u);
                acc = fmaf(fmaxf(plo + qlo, 0.f), wv[2 * i], acc);
                acc = fmaf(fmaxf(phi + qhi, 0.f), wv[2 * i + 1], acc);
            }
            part[j] = acc;
        }

        // width-8 butterfly with packing; lane gl<4 ends with edge gl's sum
        float t0 = part[0] + __shfl_xor(part[0], 1);
        float t1 = part[1] + __shfl_xor(part[1], 1);
        float t2 = part[2] + __shfl_xor(part[2], 1);
        float t3 = part[3] + __shfl_xor(part[3], 1);
        float a0 = (gl & 1) ? t1 : t0;
        float a1 = (gl & 1) ? t3 : t2;
        a0 += __shfl_xor(a0, 2);
        a1 += __shfl_xor(a1, 2);
        float c = (gl & 2) ? a1 : a0;
        c += __shfl_xor(c, 4);

        const long long e = e0 + gl;
        if (gl < 4 && e < E) atomicAdd(&out[e], c + bias);
    }
}

extern "C" void kernel_launch(void* const* d_in, const int* in_sizes, int n_in,
                              void* d_out, int out_size, void* d_ws,
                              size_t ws_size, hipStream_t stream) {
    const float* tokens = (const float*)d_in[0];
    const float* coords = (const float*)d_in[1];
    const unsigned int* idxw = (const unsigned int*)d_in[2];
    const float* w1 = (const float*)d_in[3];
    const float* b1 = (const float*)d_in[4];
    const float* w2 = (const float*)d_in[5];
    const float* b2 = (const float*)d_in[6];
    float* out = (float*)d_out;

    const int N = in_sizes[0] / CH;       // 50000
    const long long E = in_sizes[2] / 2;  // 800000
    const long long Epad = ((E + 3) >> 2) << 2;

    unsigned short* Plo = (unsigned short*)d_ws;   // [N][64] each
    unsigned short* Phi = Plo + (size_t)N * 64;
    unsigned short* Qlo = Phi + (size_t)N * 64;
    unsigned short* Qhi = Qlo + (size_t)N * 64;
    uint2* idx2 = (uint2*)(Qhi + (size_t)N * 64);
    unsigned short* Wf = (unsigned short*)(idx2 + Epad);   // 80 KB

    prep_all<<<1826, 256, 0, stream>>>(w1, b1, Wf, idxw, idx2, out, E, Epad);

    node_mfma7<<<(N + 31) / 32, 256, 0, stream>>>(tokens, coords, Wf,
                                                  Plo, Phi, Qlo, Qhi, N);

    edge_fused<<<4096, 256, 0, stream>>>((const unsigned int*)idx2,
                                         Plo, Phi, Qlo, Qhi, w2, b2, out, E);
}